// Round 6
// baseline (481.840 us; speedup 1.0000x reference)
//
#include <hip/hip_runtime.h>
#include <stdint.h>

#define L_SEQ 2048
#define NB 2
#define EMB 2048
#define II 2048
#define NH 16
#define DH 128
#define MROWS (L_SEQ * NB)  // 4096

typedef __attribute__((ext_vector_type(8))) short bf16x8;
typedef __attribute__((ext_vector_type(4))) float f32x4;
typedef unsigned short u16;
typedef unsigned int u32;

__device__ __forceinline__ u16 f2bf(float f) {
  u32 u = __builtin_bit_cast(u32, f);
  u = u + 0x7fffu + ((u >> 16) & 1u);
  return (u16)(u >> 16);
}
__device__ __forceinline__ u16 f2bf_trunc(float f) {
  return (u16)(__builtin_bit_cast(u32, f) >> 16);
}

// async global->LDS, 16B/lane; HW dest = wave-uniform base + lane*16.
__device__ __forceinline__ void gl_lds16(const void* g, const u16* l) {
  __builtin_amdgcn_global_load_lds(
      (const __attribute__((address_space(1))) void*)(uintptr_t)g,
      (__attribute__((address_space(3))) void*)(u32)(uintptr_t)l, 16, 0, 0);
}

// All five f32->bf16 casts in one launch.
__global__ __launch_bounds__(256) void cast_all(
    const float* __restrict__ q, const float* __restrict__ w0, const float* __restrict__ w1,
    const float* __restrict__ w2, const float* __restrict__ w3, u16* __restrict__ dq,
    u16* __restrict__ dw) {
  const int b = blockIdx.x, t = threadIdx.x;
  const float* src;
  u16* dst;
  int idx;
  if (b < 8192) {
    src = q; dst = dq; idx = b * 256 + t;
  } else {
    int u = b - 8192;
    int sel = u >> 12;
    src = (sel == 0) ? w0 : (sel == 1) ? w1 : (sel == 2) ? w2 : w3;
    dst = dw + (size_t)sel * II * EMB;
    idx = (u & 4095) * 256 + t;
  }
  float4 v = ((const float4*)src)[idx];
  ushort4 o;
  o.x = f2bf(v.x); o.y = f2bf(v.y); o.z = f2bf(v.z); o.w = f2bf(v.w);
  ((ushort4*)dst)[idx] = o;
}

// V [head][L][DH] -> Vt [head][DH][L], 64-l x 128-d tiles.
__global__ __launch_bounds__(256) void transpose_v(const u16* __restrict__ V,
                                                   u16* __restrict__ Vt) {
  __shared__ u16 tile[128][72];
  const int lb = blockIdx.x * 64;
  const int h = blockIdx.y;
  const u16* src = V + (size_t)h * L_SEQ * DH;
  u16* dst = Vt + (size_t)h * DH * L_SEQ;
  const int t = threadIdx.x;
  {
    const int l = t & 63, d0 = (t >> 6) * 32;
#pragma unroll
    for (int c = 0; c < 4; c++) {
      uint4 u = *(const uint4*)(src + (size_t)(lb + l) * DH + d0 + c * 8);
      const u16* e = (const u16*)&u;
#pragma unroll
      for (int x = 0; x < 8; x++) tile[d0 + c * 8 + x][l] = e[x];
    }
  }
  __syncthreads();
  {
    const int d = t >> 1, lc = (t & 1) * 32;
#pragma unroll
    for (int c = 0; c < 4; c++) {
      uint4 u = *(const uint4*)&tile[d][lc + c * 8];
      *(uint4*)(dst + (size_t)d * L_SEQ + lb + lc + c * 8) = u;
    }
  }
}

// C = A(bf16 MxK rm) * B(bf16 NdxK rm)^T + bias. BK=64, XOR-swizzled LDS.
// mode 0 (fused QKV, Nd=6144): col -> mat=col>>11 (0:Q,1:K,2:V), one head per block;
//   coalesced epilogue: acc -> LDS (reusing a/b buffers) -> 16B stores into
//   out_bf[mat*M*II + ((nb*NH+hh)*L + l)*DH + dd].
// mode 1: out_f[row*Nd+col] = acc + b0[col] (direct stores).
__global__ __launch_bounds__(256) void gemm_nt(
    const u16* __restrict__ A, const u16* __restrict__ B, const float* __restrict__ b0,
    const float* __restrict__ b1, const float* __restrict__ b2, u16* __restrict__ out_bf,
    float* __restrict__ out_f, int Nd, int K, float qscale, int mode) {
  __shared__ __align__(16) u16 sm[128 * 128];  // a:[0,8K) b:[8K,16K); epilogue: full tile
  u16* a_sm = sm;
  u16* b_sm = sm + 128 * 64;
  const int t = threadIdx.x;
  const int lane = t & 63, wv = t >> 6;
  const int quad = lane >> 4, l15 = lane & 15;
  const int x7 = l15 & 7;
  const int wm = (wv >> 1) * 64, wn = (wv & 1) * 64;
  const int m0 = blockIdx.y * 128, n0 = blockIdx.x * 128;
  const int srow = lane >> 3;                    // row-in-8 within a 1KB chunk
  const int schunk = (lane & 7) ^ (lane >> 3);   // swizzled global 16B-chunk

  f32x4 acc[4][4] = {};
  const u16* abase = A + (size_t)m0 * K;
  const u16* bbase = B + (size_t)n0 * K;

  for (int k0 = 0; k0 < K; k0 += 64) {
    __syncthreads();
#pragma unroll
    for (int j = 0; j < 4; j++) {
      int ci = wv * 4 + j;        // 16 1KB-chunks = 128 rows x 128B
      int row = ci * 8 + srow;
      gl_lds16(abase + (size_t)row * K + k0 + schunk * 8, a_sm + ci * 512);
      gl_lds16(bbase + (size_t)row * K + k0 + schunk * 8, b_sm + ci * 512);
    }
    __syncthreads();
#pragma unroll
    for (int ks = 0; ks < 2; ks++) {
      bf16x8 af[4], bfr[4];
#pragma unroll
      for (int i = 0; i < 4; i++)
        af[i] = *(const bf16x8*)(a_sm + (wm + i * 16 + l15) * 64 + ((ks * 4 + quad) ^ x7) * 8);
#pragma unroll
      for (int j = 0; j < 4; j++)
        bfr[j] = *(const bf16x8*)(b_sm + (wn + j * 16 + l15) * 64 + ((ks * 4 + quad) ^ x7) * 8);
#pragma unroll
      for (int i = 0; i < 4; i++)
#pragma unroll
        for (int j = 0; j < 4; j++)
          acc[i][j] = __builtin_amdgcn_mfma_f32_16x16x32_bf16(af[i], bfr[j], acc[i][j], 0, 0, 0);
    }
  }

  if (mode == 1) {
#pragma unroll
    for (int i = 0; i < 4; i++)
#pragma unroll
      for (int j = 0; j < 4; j++)
#pragma unroll
        for (int r = 0; r < 4; r++) {
          int row = m0 + wm + i * 16 + quad * 4 + r;
          int col = n0 + wn + j * 16 + l15;
          out_f[(size_t)row * Nd + col] = acc[i][j][r] + b0[col];
        }
    return;
  }

  // mode 0: coalesced epilogue through LDS.
  const int mat = n0 >> 11;
  const int hh = (n0 & 2047) >> 7;
  const float* bp = (mat == 0) ? b0 : (mat == 1 ? b1 : b2);
  const float sc2 = (mat == 0) ? qscale : 1.0f;
  __syncthreads();  // all frag reads of sm done
#pragma unroll
  for (int i = 0; i < 4; i++) {
#pragma unroll
    for (int j = 0; j < 4; j++) {
      float bv = bp[hh * DH + wn + j * 16 + l15];
#pragma unroll
      for (int r = 0; r < 4; r++) {
        int mr = wm + i * 16 + quad * 4 + r;   // tile row 0..127
        int dd = wn + j * 16 + l15;            // tile col 0..127
        float v = (acc[i][j][r] + bv) * sc2;
        sm[mr * 128 + (((dd >> 3) ^ (mr & 15)) << 3) + (dd & 7)] = f2bf(v);
      }
    }
  }
  __syncthreads();
  // head offset is hh * L_SEQ * DH (head-major [mat][(nb*NH+hh)][l][d])
  u16* obase = out_bf + (size_t)mat * MROWS * II + (size_t)hh * L_SEQ * DH;
  const int ch = t & 15;
#pragma unroll
  for (int s = 0; s < 8; s++) {
    int row = s * 16 + (t >> 4);
    uint4 u = *(const uint4*)(sm + row * 128 + ((ch ^ (row & 15)) << 3));
    int grow = m0 + row;
    int l = grow >> 1, nb = grow & 1;
    *(uint4*)(obase + ((size_t)(nb * NH) * L_SEQ + l) * DH + ch * 8) = u;
  }
}

// Causal flash attention v4.1. Base-2 no-max softmax (qscale folded at projection).
// 4 waves x 32 q-rows = 128-row q-tile; 128-key K-tiles; P reuses per-wave 8KB
// slice of k_sm (3 barriers/iter); LDS 64KB -> 2 blocks/CU, 512 blocks co-resident.
// Diagonal tile handled by a uniform branch (mask VALU only on last iter).
__global__ __launch_bounds__(256, 2) void flash_attn(
    const u16* __restrict__ Qh, const u16* __restrict__ Kh, const u16* __restrict__ Vt,
    u16* __restrict__ ctx) {
  __shared__ __align__(16) u16 k_sm[128 * 128];  // [key][d], chunk-swizzled
  __shared__ __align__(16) u16 v_sm[128 * 128];  // [d][key], chunk-swizzled
  const int bx = blockIdx.x;
  const int nh = ((bx & 7) << 2) | ((bx >> 3) & 3);  // 4 heads per XCD
  const int g = (bx >> 5) & 7;
  const int qt = (bx < 256) ? (15 - g) : g;  // CU-partner blocks: 17 iters combined
  const int q0 = qt * 128;
  const int nK = qt + 1;
  const int t = threadIdx.x;
  const int lane = t & 63, wv = t >> 6;
  const int quad = lane >> 4, l15 = lane & 15;
  const int x7 = l15 & 7;
  const size_t hq = (size_t)nh * L_SEQ * DH;
  const u16* qp = Qh + hq;
  const u16* kp = Kh + hq;
  const u16* vp = Vt + hq;  // [DH][L]
  const int n = nh >> 4, h = nh & 15;
  const int srow = lane >> 4;   // row-in-4 for staging (256B rows)
  const int spos = lane & 15;   // 16B chunk position
  u16* pw = k_sm + wv * 4096;   // per-wave 8KB P slice (32 rows x 256B)

  bf16x8 qf[2][4];
#pragma unroll
  for (int mi = 0; mi < 2; mi++)
#pragma unroll
    for (int ks = 0; ks < 4; ks++)
      qf[mi][ks] = *(const bf16x8*)(qp + (size_t)(q0 + wv * 32 + mi * 16 + l15) * DH +
                                    ks * 32 + quad * 8);

  f32x4 o_acc[2][8] = {};
  float l_part[2][4] = {};

#pragma unroll 1
  for (int jb = 0; jb < nK; jb++) {
    const int kb = jb * 128;
    __syncthreads();
#pragma unroll
    for (int i = 0; i < 8; i++) {
      int ci = wv * 8 + i;        // 32 1KB-chunks = 128 rows x 256B
      int row = ci * 4 + srow;
      int gc = spos ^ (row & 7);
      gl_lds16(kp + (size_t)(kb + row) * DH + gc * 8, k_sm + ci * 512);
      gl_lds16(vp + (size_t)row * L_SEQ + kb + gc * 8, v_sm + ci * 512);
    }
    __syncthreads();

    // S = Q K^T
    f32x4 s[2][8] = {};
#pragma unroll
    for (int nt = 0; nt < 8; nt++) {
#pragma unroll
      for (int ks = 0; ks < 4; ks++) {
        bf16x8 kf = *(const bf16x8*)(k_sm + (nt * 16 + l15) * 128 + ((ks * 4 + quad) ^ x7) * 8);
#pragma unroll
        for (int mi = 0; mi < 2; mi++)
          s[mi][nt] = __builtin_amdgcn_mfma_f32_16x16x32_bf16(qf[mi][ks], kf, s[mi][nt], 0, 0, 0);
      }
    }
    __syncthreads();  // all k_sm reads drained before P overwrites it

    if (jb != qt) {
#pragma unroll
      for (int mi = 0; mi < 2; mi++) {
#pragma unroll
        for (int nt = 0; nt < 8; nt++) {
#pragma unroll
          for (int r = 0; r < 4; r++) {
            float p = __builtin_amdgcn_exp2f(s[mi][nt][r]);
            l_part[mi][r] += p;
            int pr = mi * 16 + quad * 4 + r;
            int pos = (nt * 2 + (l15 >> 3)) ^ (pr & 7);
            pw[pr * 128 + pos * 8 + (l15 & 7)] = f2bf_trunc(p);
          }
        }
      }
    } else {
#pragma unroll
      for (int mi = 0; mi < 2; mi++) {
        const int rowg = q0 + wv * 32 + mi * 16 + quad * 4;
#pragma unroll
        for (int nt = 0; nt < 8; nt++) {
          const int colg = kb + nt * 16 + l15;
#pragma unroll
          for (int r = 0; r < 4; r++) {
            float p = __builtin_amdgcn_exp2f(s[mi][nt][r]);
            if (colg > rowg + r) p = 0.f;
            l_part[mi][r] += p;
            int pr = mi * 16 + quad * 4 + r;
            int pos = (nt * 2 + (l15 >> 3)) ^ (pr & 7);
            pw[pr * 128 + pos * 8 + (l15 & 7)] = f2bf_trunc(p);
          }
        }
      }
    }
    __asm__ volatile("s_waitcnt lgkmcnt(0)" ::: "memory");

    // O += P V
    bf16x8 pf[2][4];
#pragma unroll
    for (int mi = 0; mi < 2; mi++)
#pragma unroll
      for (int ks = 0; ks < 4; ks++)
        pf[mi][ks] = *(const bf16x8*)(pw + (mi * 16 + l15) * 128 + ((ks * 4 + quad) ^ x7) * 8);
#pragma unroll
    for (int nt = 0; nt < 8; nt++) {
#pragma unroll
      for (int ks = 0; ks < 4; ks++) {
        bf16x8 vf = *(const bf16x8*)(v_sm + (nt * 16 + l15) * 128 + ((ks * 4 + quad) ^ x7) * 8);
#pragma unroll
        for (int mi = 0; mi < 2; mi++)
          o_acc[mi][nt] =
              __builtin_amdgcn_mfma_f32_16x16x32_bf16(pf[mi][ks], vf, o_acc[mi][nt], 0, 0, 0);
      }
    }
  }

#pragma unroll
  for (int mi = 0; mi < 2; mi++) {
#pragma unroll
    for (int r = 0; r < 4; r++) {
      float lv = l_part[mi][r];
#pragma unroll
      for (int off = 1; off < 16; off <<= 1) lv += __shfl_xor(lv, off, 64);
      float inv = 1.f / lv;
      const int lrow = q0 + wv * 32 + mi * 16 + quad * 4 + r;
#pragma unroll
      for (int nt = 0; nt < 8; nt++) {
        int dd = nt * 16 + l15;
        ctx[((size_t)lrow * NB + n) * EMB + h * DH + dd] = f2bf(o_acc[mi][nt][r] * inv);
      }
    }
  }
}

extern "C" void kernel_launch(void* const* d_in, const int* in_sizes, int n_in,
                              void* d_out, int out_size, void* d_ws, size_t ws_size,
                              hipStream_t stream) {
  const float* query    = (const float*)d_in[0];
  const float* q_proj   = (const float*)d_in[1];
  const float* q_bias   = (const float*)d_in[2];
  const float* k_proj   = (const float*)d_in[3];
  const float* k_bias   = (const float*)d_in[4];
  const float* v_proj   = (const float*)d_in[5];
  const float* v_bias   = (const float*)d_in[6];
  const float* out_proj = (const float*)d_in[7];
  const float* out_bias = (const float*)d_in[8];

  u16* ws  = (u16*)d_ws;
  u16* Xbf = ws;                                  // 4096x2048 (dead after QKV gemm)
  u16* Wq  = Xbf + (size_t)MROWS * EMB;           // Wq|Wk|Wv contiguous = [6144,2048]
  u16* Wk  = Wq + (size_t)II * EMB;
  u16* Wv  = Wk + (size_t)II * EMB;
  u16* Wo  = Wv + (size_t)II * EMB;
  u16* Qw  = Wo + (size_t)EMB * II;               // [NB*NH][L][DH], Q|K|V contiguous
  u16* Kw  = Qw + (size_t)MROWS * II;
  u16* Vw  = Kw + (size_t)MROWS * II;
  u16* Cw  = Vw + (size_t)MROWS * II;             // ctx [L][NB][EMB]
  u16* Vtb = Xbf;                                 // Vt [NB*NH][DH][L] aliases Xbf

  cast_all<<<8192 + 4 * 4096, 256, 0, stream>>>(query, q_proj, k_proj, v_proj, out_proj,
                                                Xbf, Wq);

  // d^-0.5 * log2(e): base-2 softmax
  const float qscale = 0.08838834764831845f * 1.4426950408889634f;
  gemm_nt<<<dim3(3 * II / 128, MROWS / 128), 256, 0, stream>>>(
      Xbf, Wq, q_bias, k_bias, v_bias, Qw, nullptr, 3 * II, EMB, qscale, 0);

  transpose_v<<<dim3(L_SEQ / 64, NB * NH), 256, 0, stream>>>(Vw, Vtb);

  flash_attn<<<512, 256, 0, stream>>>(Qw, Kw, Vtb, Cw);

  gemm_nt<<<dim3(EMB / 128, MROWS / 128), 256, 0, stream>>>(
      Cw, Wo, out_bias, nullptr, nullptr, nullptr, (float*)d_out, EMB, II, 1.0f, 1);
}

// Round 7
// 465.406 us; speedup vs baseline: 1.0353x; 1.0353x over previous
//
#include <hip/hip_runtime.h>
#include <stdint.h>

#define L_SEQ 2048
#define NB 2
#define EMB 2048
#define II 2048
#define NH 16
#define DH 128
#define MROWS (L_SEQ * NB)  // 4096

typedef __attribute__((ext_vector_type(8))) short bf16x8;
typedef __attribute__((ext_vector_type(4))) float f32x4;
typedef unsigned short u16;
typedef unsigned int u32;

__device__ __forceinline__ u16 f2bf(float f) {
  u32 u = __builtin_bit_cast(u32, f);
  u = u + 0x7fffu + ((u >> 16) & 1u);
  return (u16)(u >> 16);
}
__device__ __forceinline__ u16 f2bf_trunc(float f) {
  return (u16)(__builtin_bit_cast(u32, f) >> 16);
}

// async global->LDS, 16B/lane; HW dest = wave-uniform base + lane*16.
__device__ __forceinline__ void gl_lds16(const void* g, const u16* l) {
  __builtin_amdgcn_global_load_lds(
      (const __attribute__((address_space(1))) void*)(uintptr_t)g,
      (__attribute__((address_space(3))) void*)(u32)(uintptr_t)l, 16, 0, 0);
}

// All five f32->bf16 casts in one launch.
__global__ __launch_bounds__(256) void cast_all(
    const float* __restrict__ q, const float* __restrict__ w0, const float* __restrict__ w1,
    const float* __restrict__ w2, const float* __restrict__ w3, u16* __restrict__ dq,
    u16* __restrict__ dw) {
  const int b = blockIdx.x, t = threadIdx.x;
  const float* src;
  u16* dst;
  int idx;
  if (b < 8192) {
    src = q; dst = dq; idx = b * 256 + t;
  } else {
    int u = b - 8192;
    int sel = u >> 12;
    src = (sel == 0) ? w0 : (sel == 1) ? w1 : (sel == 2) ? w2 : w3;
    dst = dw + (size_t)sel * II * EMB;
    idx = (u & 4095) * 256 + t;
  }
  float4 v = ((const float4*)src)[idx];
  ushort4 o;
  o.x = f2bf(v.x); o.y = f2bf(v.y); o.z = f2bf(v.z); o.w = f2bf(v.w);
  ((ushort4*)dst)[idx] = o;
}

// V [head][L][DH] -> Vt [head][DH][L], 64-l x 128-d tiles.
__global__ __launch_bounds__(256) void transpose_v(const u16* __restrict__ V,
                                                   u16* __restrict__ Vt) {
  __shared__ u16 tile[128][72];
  const int lb = blockIdx.x * 64;
  const int h = blockIdx.y;
  const u16* src = V + (size_t)h * L_SEQ * DH;
  u16* dst = Vt + (size_t)h * DH * L_SEQ;
  const int t = threadIdx.x;
  {
    const int l = t & 63, d0 = (t >> 6) * 32;
#pragma unroll
    for (int c = 0; c < 4; c++) {
      uint4 u = *(const uint4*)(src + (size_t)(lb + l) * DH + d0 + c * 8);
      const u16* e = (const u16*)&u;
#pragma unroll
      for (int x = 0; x < 8; x++) tile[d0 + c * 8 + x][l] = e[x];
    }
  }
  __syncthreads();
  {
    const int d = t >> 1, lc = (t & 1) * 32;
#pragma unroll
    for (int c = 0; c < 4; c++) {
      uint4 u = *(const uint4*)&tile[d][lc + c * 8];
      *(uint4*)(dst + (size_t)d * L_SEQ + lb + lc + c * 8) = u;
    }
  }
}

// C = A(bf16 MxK rm) * B(bf16 NdxK rm)^T + bias. BK=64, XOR-swizzled LDS.
// mode 0 (fused QKV): coalesced LDS epilogue into head-major [mat][nb*NH+hh][l][d].
// mode 1: out_f[row*Nd+col] = acc + b0[col] (direct stores).
__global__ __launch_bounds__(256) void gemm_nt(
    const u16* __restrict__ A, const u16* __restrict__ B, const float* __restrict__ b0,
    const float* __restrict__ b1, const float* __restrict__ b2, u16* __restrict__ out_bf,
    float* __restrict__ out_f, int Nd, int K, float qscale, int mode) {
  __shared__ __align__(16) u16 sm[128 * 128];  // a:[0,8K) b:[8K,16K); epilogue: full tile
  u16* a_sm = sm;
  u16* b_sm = sm + 128 * 64;
  const int t = threadIdx.x;
  const int lane = t & 63, wv = t >> 6;
  const int quad = lane >> 4, l15 = lane & 15;
  const int x7 = l15 & 7;
  const int wm = (wv >> 1) * 64, wn = (wv & 1) * 64;
  const int m0 = blockIdx.y * 128, n0 = blockIdx.x * 128;
  const int srow = lane >> 3;                    // row-in-8 within a 1KB chunk
  const int schunk = (lane & 7) ^ (lane >> 3);   // swizzled global 16B-chunk

  f32x4 acc[4][4] = {};
  const u16* abase = A + (size_t)m0 * K;
  const u16* bbase = B + (size_t)n0 * K;

  for (int k0 = 0; k0 < K; k0 += 64) {
    __syncthreads();
#pragma unroll
    for (int j = 0; j < 4; j++) {
      int ci = wv * 4 + j;        // 16 1KB-chunks = 128 rows x 128B
      int row = ci * 8 + srow;
      gl_lds16(abase + (size_t)row * K + k0 + schunk * 8, a_sm + ci * 512);
      gl_lds16(bbase + (size_t)row * K + k0 + schunk * 8, b_sm + ci * 512);
    }
    __syncthreads();
#pragma unroll
    for (int ks = 0; ks < 2; ks++) {
      bf16x8 af[4], bfr[4];
#pragma unroll
      for (int i = 0; i < 4; i++)
        af[i] = *(const bf16x8*)(a_sm + (wm + i * 16 + l15) * 64 + ((ks * 4 + quad) ^ x7) * 8);
#pragma unroll
      for (int j = 0; j < 4; j++)
        bfr[j] = *(const bf16x8*)(b_sm + (wn + j * 16 + l15) * 64 + ((ks * 4 + quad) ^ x7) * 8);
#pragma unroll
      for (int i = 0; i < 4; i++)
#pragma unroll
        for (int j = 0; j < 4; j++)
          acc[i][j] = __builtin_amdgcn_mfma_f32_16x16x32_bf16(af[i], bfr[j], acc[i][j], 0, 0, 0);
    }
  }

  if (mode == 1) {
#pragma unroll
    for (int i = 0; i < 4; i++)
#pragma unroll
      for (int j = 0; j < 4; j++)
#pragma unroll
        for (int r = 0; r < 4; r++) {
          int row = m0 + wm + i * 16 + quad * 4 + r;
          int col = n0 + wn + j * 16 + l15;
          out_f[(size_t)row * Nd + col] = acc[i][j][r] + b0[col];
        }
    return;
  }

  // mode 0: coalesced epilogue through LDS.
  const int mat = n0 >> 11;
  const int hh = (n0 & 2047) >> 7;
  const float* bp = (mat == 0) ? b0 : (mat == 1 ? b1 : b2);
  const float sc2 = (mat == 0) ? qscale : 1.0f;
  __syncthreads();  // all frag reads of sm done
#pragma unroll
  for (int i = 0; i < 4; i++) {
#pragma unroll
    for (int j = 0; j < 4; j++) {
      float bv = bp[hh * DH + wn + j * 16 + l15];
#pragma unroll
      for (int r = 0; r < 4; r++) {
        int mr = wm + i * 16 + quad * 4 + r;   // tile row 0..127
        int dd = wn + j * 16 + l15;            // tile col 0..127
        float v = (acc[i][j][r] + bv) * sc2;
        sm[mr * 128 + (((dd >> 3) ^ (mr & 15)) << 3) + (dd & 7)] = f2bf(v);
      }
    }
  }
  __syncthreads();
  u16* obase = out_bf + (size_t)mat * MROWS * II + (size_t)hh * L_SEQ * DH;
  const int ch = t & 15;
#pragma unroll
  for (int s = 0; s < 8; s++) {
    int row = s * 16 + (t >> 4);
    uint4 u = *(const uint4*)(sm + row * 128 + ((ch ^ (row & 15)) << 3));
    int grow = m0 + row;
    int l = grow >> 1, nb = grow & 1;
    *(uint4*)(obase + ((size_t)(nb * NH) * L_SEQ + l) * DH + ch * 8) = u;
  }
}

// Causal flash attention v5 — barrier-free. K and V^T fragments loaded directly
// from global (L2-resident: 4 heads/XCD = 4MB working set); only P round-trips
// through a per-wave private 4KB LDS slice (lgkmcnt-only sync). 128-thread
// blocks = 2 waves x 32 q-rows = 64-row tile; 64-key K-tiles; grid 1024 =
// 4 blocks/CU co-resident, per-CU iteration sums balanced by construction.
__global__ __launch_bounds__(128, 2) void flash_attn(
    const u16* __restrict__ Qh, const u16* __restrict__ Kh, const u16* __restrict__ Vt,
    u16* __restrict__ ctx) {
  __shared__ __align__(16) u16 p_sm[2][32 * 64];  // per-wave 4KB, chunk-swizzled
  const int bx = blockIdx.x;
  const int ii = bx & 255, jj = bx >> 8;          // CU-slot, round index
  const int nh = (ii & 7) * 4 + jj;               // 4 heads per XCD (bx%8 ~ XCD)
  const int a = ii >> 3;                          // 0..31
  const int qt = (jj & 1) ? a : (31 - a);         // per-CU sums constant
  const int q0 = qt * 64;
  const int nK = qt + 1;
  const int t = threadIdx.x;
  const int lane = t & 63, wv = t >> 6;
  const int quad = lane >> 4, l15 = lane & 15;
  const int x7 = l15 & 7;
  const size_t hq = (size_t)nh * L_SEQ * DH;
  const u16* qp = Qh + hq;
  const u16* kp = Kh + hq;
  const u16* vp = Vt + hq;  // [DH][L]
  const int n = nh >> 4, h = nh & 15;
  u16* pw = (u16*)p_sm[wv];

  // Q fragments: rows q0 + wv*32 + mi*16 + l15.
  bf16x8 qf[2][4];
#pragma unroll
  for (int mi = 0; mi < 2; mi++)
#pragma unroll
    for (int ks = 0; ks < 4; ks++)
      qf[mi][ks] = *(const bf16x8*)(qp + (size_t)(q0 + wv * 32 + mi * 16 + l15) * DH +
                                    ks * 32 + quad * 8);

  f32x4 o_acc[2][8] = {};
  float l_part[2][4] = {};

#pragma unroll 1
  for (int jb = 0; jb < nK; jb++) {
    const int kb = jb * 64;

    // S = Q K^T — K fragments straight from global (compiler interleaves vmcnt)
    f32x4 s[2][4] = {};
#pragma unroll
    for (int nt = 0; nt < 4; nt++) {
#pragma unroll
      for (int ks = 0; ks < 4; ks++) {
        bf16x8 kf = *(const bf16x8*)(kp + (size_t)(kb + nt * 16 + l15) * DH + ks * 32 + quad * 8);
#pragma unroll
        for (int mi = 0; mi < 2; mi++)
          s[mi][nt] = __builtin_amdgcn_mfma_f32_16x16x32_bf16(qf[mi][ks], kf, s[mi][nt], 0, 0, 0);
      }
    }

    // base-2 softmax (no max subtraction; scores small by construction)
    if (jb != nK - 1) {
#pragma unroll
      for (int mi = 0; mi < 2; mi++)
#pragma unroll
        for (int nt = 0; nt < 4; nt++)
#pragma unroll
          for (int r = 0; r < 4; r++) {
            float p = __builtin_amdgcn_exp2f(s[mi][nt][r]);
            l_part[mi][r] += p;
            int pr = mi * 16 + quad * 4 + r;
            int pos = (nt * 2 + (l15 >> 3)) ^ (pr & 7);
            pw[pr * 64 + pos * 8 + (l15 & 7)] = f2bf_trunc(p);
          }
    } else {
#pragma unroll
      for (int mi = 0; mi < 2; mi++) {
        const int rowg = q0 + wv * 32 + mi * 16 + quad * 4;
#pragma unroll
        for (int nt = 0; nt < 4; nt++) {
          const int colg = kb + nt * 16 + l15;
#pragma unroll
          for (int r = 0; r < 4; r++) {
            float p = __builtin_amdgcn_exp2f(s[mi][nt][r]);
            if (colg > rowg + r) p = 0.f;
            l_part[mi][r] += p;
            int pr = mi * 16 + quad * 4 + r;
            int pos = (nt * 2 + (l15 >> 3)) ^ (pr & 7);
            pw[pr * 64 + pos * 8 + (l15 & 7)] = f2bf_trunc(p);
          }
        }
      }
    }
    __asm__ volatile("s_waitcnt lgkmcnt(0)" ::: "memory");  // wave-local P visible

    // O += P V — V^T fragments straight from global
    bf16x8 pf[2][2];
#pragma unroll
    for (int mi = 0; mi < 2; mi++)
#pragma unroll
      for (int ks = 0; ks < 2; ks++)
        pf[mi][ks] = *(const bf16x8*)(pw + (mi * 16 + l15) * 64 + ((ks * 4 + quad) ^ x7) * 8);
#pragma unroll
    for (int nt = 0; nt < 8; nt++) {
#pragma unroll
      for (int ks = 0; ks < 2; ks++) {
        bf16x8 vf = *(const bf16x8*)(vp + (size_t)(nt * 16 + l15) * L_SEQ + kb + ks * 32 + quad * 8);
#pragma unroll
        for (int mi = 0; mi < 2; mi++)
          o_acc[mi][nt] =
              __builtin_amdgcn_mfma_f32_16x16x32_bf16(pf[mi][ks], vf, o_acc[mi][nt], 0, 0, 0);
      }
    }
  }

  // Epilogue: reduce denominators across the 16-lane row group, write ctx.
#pragma unroll
  for (int mi = 0; mi < 2; mi++) {
#pragma unroll
    for (int r = 0; r < 4; r++) {
      float lv = l_part[mi][r];
#pragma unroll
      for (int off = 1; off < 16; off <<= 1) lv += __shfl_xor(lv, off, 64);
      float inv = 1.f / lv;
      const int lrow = q0 + wv * 32 + mi * 16 + quad * 4 + r;
#pragma unroll
      for (int nt = 0; nt < 8; nt++) {
        int dd = nt * 16 + l15;
        ctx[((size_t)lrow * NB + n) * EMB + h * DH + dd] = f2bf(o_acc[mi][nt][r] * inv);
      }
    }
  }
}

extern "C" void kernel_launch(void* const* d_in, const int* in_sizes, int n_in,
                              void* d_out, int out_size, void* d_ws, size_t ws_size,
                              hipStream_t stream) {
  const float* query    = (const float*)d_in[0];
  const float* q_proj   = (const float*)d_in[1];
  const float* q_bias   = (const float*)d_in[2];
  const float* k_proj   = (const float*)d_in[3];
  const float* k_bias   = (const float*)d_in[4];
  const float* v_proj   = (const float*)d_in[5];
  const float* v_bias   = (const float*)d_in[6];
  const float* out_proj = (const float*)d_in[7];
  const float* out_bias = (const float*)d_in[8];

  u16* ws  = (u16*)d_ws;
  u16* Xbf = ws;                                  // 4096x2048 (dead after QKV gemm)
  u16* Wq  = Xbf + (size_t)MROWS * EMB;           // Wq|Wk|Wv contiguous = [6144,2048]
  u16* Wk  = Wq + (size_t)II * EMB;
  u16* Wv  = Wk + (size_t)II * EMB;
  u16* Wo  = Wv + (size_t)II * EMB;
  u16* Qw  = Wo + (size_t)EMB * II;               // [NB*NH][L][DH], Q|K|V contiguous
  u16* Kw  = Qw + (size_t)MROWS * II;
  u16* Vw  = Kw + (size_t)MROWS * II;
  u16* Cw  = Vw + (size_t)MROWS * II;             // ctx [L][NB][EMB]
  u16* Vtb = Xbf;                                 // Vt [NB*NH][DH][L] aliases Xbf

  cast_all<<<8192 + 4 * 4096, 256, 0, stream>>>(query, q_proj, k_proj, v_proj, out_proj,
                                                Xbf, Wq);

  // d^-0.5 * log2(e): base-2 softmax
  const float qscale = 0.08838834764831845f * 1.4426950408889634f;
  gemm_nt<<<dim3(3 * II / 128, MROWS / 128), 256, 0, stream>>>(
      Xbf, Wq, q_bias, k_bias, v_bias, Qw, nullptr, 3 * II, EMB, qscale, 0);

  transpose_v<<<dim3(L_SEQ / 64, NB * NH), 256, 0, stream>>>(Vw, Vtb);

  flash_attn<<<1024, 128, 0, stream>>>(Qw, Kw, Vtb, Cw);

  gemm_nt<<<dim3(EMB / 128, MROWS / 128), 256, 0, stream>>>(
      Cw, Wo, out_bias, nullptr, nullptr, nullptr, (float*)d_out, EMB, II, 1.0f, 1);
}